// Round 20
// baseline (1550.600 us; speedup 1.0000x reference)
//
#include <hip/hip_runtime.h>
#include <hip/hip_bf16.h>

#define NQ 200
#define PFX 5
#define NPATCH 1600
#define NT 1805
#define DM 1024
#define NHEAD 16
#define DHEAD 64
#define NBLK 4
#define NCLS 151
#define NKT 29     // ceil(1805/64) kv tiles
#define NWRD 57    // ceil(1805/32) mask words per query row
#define VTS 1856   // V^T row stride (NKT*64, 16B-aligned)

typedef short s16x8 __attribute__((ext_vector_type(8)));
typedef float f32x4 __attribute__((ext_vector_type(4)));

__device__ __forceinline__ float gelu_f(float x) {
  return 0.5f * x * (1.0f + erff(x * 0.7071067811865476f));
}
__device__ __forceinline__ short f2bf(float x) {
  __hip_bfloat16 h = __float2bfloat16(x);
  return *reinterpret_cast<short*>(&h);
}
__device__ __forceinline__ float bf2f(short s) {
  __hip_bfloat16 h;
  *reinterpret_cast<short*>(&h) = s;
  return __bfloat162float(h);
}
// async 16B global->LDS (width literal 16). LDS dest wave-uniform base + lane*16B.
__device__ __forceinline__ void glds16(const void* g, void* l) {
  __builtin_amdgcn_global_load_lds(
      (const __attribute__((address_space(1))) void*)g,
      (__attribute__((address_space(3))) void*)l, 16, 0, 0);
}

// ---------------- concat: x = [q_weight ; x_tokens] ----------------
__global__ __launch_bounds__(256) void concat_kernel(const float* __restrict__ qw,
    const float* __restrict__ xt, float* __restrict__ x) {
  int idx = blockIdx.x * 256 + threadIdx.x;
  if (idx >= NT * DM) return;
  int n = idx >> 10;
  x[idx] = (n < NQ) ? qw[idx] : xt[idx - NQ * DM];
}

// ---------------- weight transpose+split: W (K x N fp32) -> Th/Tl (N x K bf16) ----------------
__global__ __launch_bounds__(256) void cvtT_kernel(const float* __restrict__ W,
    short* __restrict__ Th, short* __restrict__ Tl, int K, int N) {
  __shared__ float t[32][33];
  const int n0 = blockIdx.x * 32, k0 = blockIdx.y * 32;
  const int tx = threadIdx.x & 31, ty = threadIdx.x >> 5;
#pragma unroll
  for (int i = 0; i < 32; i += 8)
    t[ty + i][tx] = W[(size_t)(k0 + ty + i) * N + n0 + tx];
  __syncthreads();
#pragma unroll
  for (int i = 0; i < 32; i += 8) {
    int n = n0 + ty + i, k = k0 + tx;
    float xv = t[tx][ty + i];
    short hh = f2bf(xv);
    Th[(size_t)n * K + k] = hh;
    Tl[(size_t)n * K + k] = f2bf(xv - bf2f(hh));
  }
}

// ---------------- LayerNorm -> bf16 hi/lo ----------------
__global__ __launch_bounds__(256) void ln_kernel(const float* __restrict__ in,
    const float* __restrict__ g, const float* __restrict__ b,
    short* __restrict__ oh, short* __restrict__ ol) {
  const int row = blockIdx.x;
  const int tid = threadIdx.x;
  const float* x = in + (size_t)row * DM;
  float v[4];
#pragma unroll
  for (int i = 0; i < 4; ++i) v[i] = x[tid + (i << 8)];
  float s = v[0] + v[1] + v[2] + v[3];
  __shared__ float red[4];
  __shared__ float red2[4];
#pragma unroll
  for (int off = 32; off; off >>= 1) s += __shfl_down(s, off, 64);
  if ((tid & 63) == 0) red[tid >> 6] = s;
  __syncthreads();
  float mean = (red[0] + red[1] + red[2] + red[3]) * (1.0f / DM);
  float sq = 0.f;
#pragma unroll
  for (int i = 0; i < 4; ++i) { float d = v[i] - mean; sq += d * d; }
#pragma unroll
  for (int off = 32; off; off >>= 1) sq += __shfl_down(sq, off, 64);
  if ((tid & 63) == 0) red2[tid >> 6] = sq;
  __syncthreads();
  float var = (red2[0] + red2[1] + red2[2] + red2[3]) * (1.0f / DM);
  float inv = 1.0f / sqrtf(var + 1e-6f);
#pragma unroll
  for (int i = 0; i < 4; ++i) {
    int d = tid + (i << 8);
    float y = (v[i] - mean) * inv * g[d] + b[d];
    short hh = f2bf(y);
    oh[(size_t)row * DM + d] = hh;
    ol[(size_t)row * DM + d] = f2bf(y - bf2f(hh));
  }
}

// ---------------- bf16 MFMA GEMM: dbuf LDS + split-K + fused epilogues ----------------
// ALO=1: 3-term; ALO=0: 2-term (A hi-only).
// OMODE: 0 bf16 h/l out (+ACT); 1 fp32 out (+ACT); 2 atomicAdd fp32 (bias z==0);
//        3 partial fp32 at Cf + z*M*N (bias z==0);
//        4 bf16 HI-only out (+ACT);
//        5 fused residual: atomicAdd(Cf[o], lsv[col]*(v+bias)) (bias z==0);
//        7 qkv layout: Q->Ch[row][2048]+Cl[row][1024], K->Ch hi, V->V^T[(col-2048)][row]
//          (V^T buffer passed via Cf, stride VTS).
template <int BM64, int BSRC, int ALO, int ACT, int OMODE, int KS>
__global__ __launch_bounds__(256) void mgemm_kernel(
    const short* __restrict__ Ah, const short* __restrict__ Al,
    const float* __restrict__ Wf,
    const short* __restrict__ Bh, const short* __restrict__ Bl,
    const float* __restrict__ bias, const float* __restrict__ lsv,
    float* __restrict__ Cf, short* __restrict__ Ch, short* __restrict__ Cl,
    int M, int N, int K) {
  constexpr int BM = BM64 ? 64 : 128;
  constexpr int AT = BM64 ? 2 : 4;
  constexpr int AISS = BM64 ? 1 : 2;
  __shared__ __align__(16) short sAh[2 * BM * 32];
  __shared__ __align__(16) short sAl[ALO ? 2 * BM * 32 : 8];
  __shared__ __align__(16) short sBh[2 * 128 * 32], sBl[2 * 128 * 32];
  const int tid = threadIdx.x;
  const int lane = tid & 63;
  const int w = tid >> 6;
  const int bm = blockIdx.y * BM;
  const int bn = blockIdx.x << 7;
  const int z = (KS > 1) ? blockIdx.z : 0;
  const int KL = K / KS;
  const int kbase = z * KL;

  f32x4 acc[AT][4];
  {
    f32x4 zf = {0.f, 0.f, 0.f, 0.f};
#pragma unroll
    for (int mi = 0; mi < AT; ++mi)
#pragma unroll
      for (int ni = 0; ni < 4; ++ni) acc[mi][ni] = zf;
  }

  auto issueA = [&](int buf, int k0) {
#pragma unroll
    for (int i = 0; i < AISS; ++i) {
      int br = (BM64 ? (w << 4) : (w << 5) + (i << 4));
      int r = br + (lane >> 2);
      int cg = (lane & 3) ^ ((r >> 1) & 3);
      size_t go = (size_t)min(bm + r, M - 1) * K + kbase + k0 + (cg << 3);
      glds16(Ah + go, &sAh[(buf * BM + br) * 32]);
      if (ALO) glds16(Al + go, &sAl[(buf * BM + br) * 32]);
    }
  };
  auto issueB1 = [&](int buf, int k0) {
#pragma unroll
    for (int i = 0; i < 2; ++i) {
      int br = (w << 5) + (i << 4);
      int r = br + (lane >> 2);
      int cg = (lane & 3) ^ ((r >> 1) & 3);
      size_t go = (size_t)min(bn + r, N - 1) * K + kbase + k0 + (cg << 3);
      glds16(Bh + go, &sBh[(buf * 128 + br) * 32]);
      glds16(Bl + go, &sBl[(buf * 128 + br) * 32]);
    }
  };
  float wv[2][8];
  auto loadB0 = [&](int k0) {
#pragma unroll
    for (int p = 0; p < 2; ++p) {
      int n = tid & 127;
      int c8 = (tid >> 7) + (p << 1);
      const float* Wp = Wf + (size_t)(kbase + k0 + (c8 << 3)) * N + min(bn + n, N - 1);
#pragma unroll
      for (int j = 0; j < 8; ++j) wv[p][j] = Wp[(size_t)j * N];
    }
  };
  auto writeB0 = [&](int buf) {
#pragma unroll
    for (int p = 0; p < 2; ++p) {
      int n = tid & 127;
      int c8 = (tid >> 7) + (p << 1);
      int cp = c8 ^ ((n >> 1) & 3);
      union { uint4 u; short e[8]; } H, L;
#pragma unroll
      for (int j = 0; j < 8; ++j) {
        short hh = f2bf(wv[p][j]);
        H.e[j] = hh;
        L.e[j] = f2bf(wv[p][j] - bf2f(hh));
      }
      int off = (buf * 128 + n) * 32 + (cp << 3);
      *(uint4*)&sBh[off] = H.u;
      *(uint4*)&sBl[off] = L.u;
    }
  };

  issueA(0, 0);
  if (BSRC == 1) issueB1(0, 0);
  else { loadB0(0); writeB0(0); }
  __syncthreads();

  const int nt = KL >> 5;
  int cur = 0;
  const int ar = lane & 15;
  const int kc = lane >> 4;
  const int wmr = BM64 ? ((w >> 1) << 5) : ((w >> 1) << 6);
  const int wnr = (w & 1) << 6;

  for (int t = 0; t < nt; ++t) {
    const bool more = (t + 1 < nt);
    if (more) {
      int k0n = (t + 1) << 5;
      issueA(cur ^ 1, k0n);
      if (BSRC == 1) issueB1(cur ^ 1, k0n);
      else loadB0(k0n);
    }
    s16x8 fah[AT], fal[AT], fbh[4], fbl[4];
#pragma unroll
    for (int t2 = 0; t2 < AT; ++t2) {
      int r = wmr + (t2 << 4) + ar;
      int off = (cur * BM + r) * 32 + ((kc ^ ((r >> 1) & 3)) << 3);
      fah[t2] = *(const s16x8*)&sAh[off];
      if (ALO) fal[t2] = *(const s16x8*)&sAl[off];
    }
#pragma unroll
    for (int t2 = 0; t2 < 4; ++t2) {
      int r = wnr + (t2 << 4) + ar;
      int off = (cur * 128 + r) * 32 + ((kc ^ ((r >> 1) & 3)) << 3);
      fbh[t2] = *(const s16x8*)&sBh[off];
      fbl[t2] = *(const s16x8*)&sBl[off];
    }
#pragma unroll
    for (int mi = 0; mi < AT; ++mi)
#pragma unroll
      for (int ni = 0; ni < 4; ++ni) {
        acc[mi][ni] = __builtin_amdgcn_mfma_f32_16x16x32_bf16(fah[mi], fbh[ni], acc[mi][ni], 0, 0, 0);
        acc[mi][ni] = __builtin_amdgcn_mfma_f32_16x16x32_bf16(fah[mi], fbl[ni], acc[mi][ni], 0, 0, 0);
        if (ALO)
          acc[mi][ni] = __builtin_amdgcn_mfma_f32_16x16x32_bf16(fal[mi], fbh[ni], acc[mi][ni], 0, 0, 0);
      }
    if (more) {
      if (BSRC == 0) writeB0(cur ^ 1);
      __syncthreads();
      cur ^= 1;
    }
  }

  const int erow = bm + wmr + ((lane >> 4) << 2);
  const int ecol = bn + wnr + (lane & 15);
  float bv[4], lv[4];
#pragma unroll
  for (int ni = 0; ni < 4; ++ni) {
    int col = ecol + ni * 16;
    float b0 = (bias != nullptr && col < N) ? bias[col] : 0.f;
    bv[ni] = (KS > 1 && z != 0) ? 0.f : b0;
    lv[ni] = (OMODE == 5 && col < N) ? lsv[col] : 0.f;
  }
#pragma unroll
  for (int mi = 0; mi < AT; ++mi) {
#pragma unroll
    for (int rr = 0; rr < 4; ++rr) {
      int row = erow + mi * 16 + rr;
      if (row >= M) continue;
#pragma unroll
      for (int ni = 0; ni < 4; ++ni) {
        int col = ecol + ni * 16;
        if (col >= N) continue;
        float v = acc[mi][ni][rr] + bv[ni];
        size_t o = (size_t)row * N + col;
        if (OMODE == 0) {
          if (ACT == 1) v = gelu_f(v);
          short hh = f2bf(v);
          Ch[o] = hh;
          Cl[o] = f2bf(v - bf2f(hh));
        } else if (OMODE == 1) {
          if (ACT == 1) v = gelu_f(v);
          Cf[o] = v;
        } else if (OMODE == 2) {
          atomicAdd(&Cf[o], v);
        } else if (OMODE == 3) {
          Cf[(size_t)z * M * N + o] = v;
        } else if (OMODE == 4) {
          if (ACT == 1) v = gelu_f(v);
          Ch[o] = f2bf(v);
        } else if (OMODE == 5) {
          atomicAdd(&Cf[o], lv[ni] * v);
        } else {  // OMODE == 7: qkv split layout + V^T emission
          short hh = f2bf(v);
          if (col < 1024) {
            Ch[(size_t)row * 2048 + col] = hh;
            Cl[(size_t)row * 1024 + col] = f2bf(v - bf2f(hh));
          } else if (col < 2048) {
            Ch[(size_t)row * 2048 + col] = hh;
          } else {
            ((short*)Cf)[(size_t)(col - 2048) * VTS + row] = hh;
          }
        }
      }
    }
  }
}

// ---------------- split-K partial reduce (+act, +bf16 hi/lo split) ----------------
template <int ACT, int WSPLIT>
__global__ __launch_bounds__(256) void redsplit_kernel(const float* __restrict__ pb,
    float* __restrict__ outf, short* __restrict__ oh, short* __restrict__ ol,
    int KSr, int MN) {
  int idx = blockIdx.x * 256 + threadIdx.x;
  if (idx >= MN) return;
  float s = 0.f;
  for (int zz = 0; zz < KSr; ++zz) s += pb[(size_t)zz * MN + idx];
  if (ACT == 1) s = gelu_f(s);
  if (WSPLIT) {
    short hh = f2bf(s);
    oh[idx] = hh;
    ol[idx] = f2bf(s - bf2f(hh));
  } else {
    outf[idx] = s;
  }
}

// ---------------- pack attention keep-mask into bits ----------------
__global__ __launch_bounds__(256) void maskpack_kernel(const float* __restrict__ mlog,
    unsigned* __restrict__ bits) {
  int idx = blockIdx.x * 256 + threadIdx.x;
  if (idx >= NQ * NWRD) return;
  int q = idx / NWRD, w = idx - q * NWRD;
  unsigned word = 0u;
  int c0 = w * 32;
#pragma unroll
  for (int b = 0; b < 32; ++b) {
    int c = c0 + b;
    unsigned keep;
    if (c < NQ + PFX) keep = 1u;
    else if (c < NT) keep = (mlog[(size_t)q * NPATCH + (c - NQ - PFX)] > 0.f) ? 1u : 0u;
    else keep = 0u;
    word |= keep << b;
  }
  bits[idx] = word;
}

// ---------------- flash attention: glds16-staged K & pre-transposed V ----------------
// qkh: [NT][2048] Q|K hi. ql: [NT][1024] Q lo. vt: [1024][VTS] V^T hi.
// S = (Qh+Ql)·Kh; PV 1-term. One barrier/tile; tile t+2 issued after barrier of t.
__global__ __launch_bounds__(256, 2) void fattn_kernel(
    const short* __restrict__ qkh, const short* __restrict__ ql,
    const short* __restrict__ vt, const unsigned* __restrict__ bits,
    short* __restrict__ ao_h) {
  const int bid = blockIdx.x;
  const int h = bid & 15;
  const int q0 = (bid >> 4) * 64;
  const int tid = threadIdx.x;
  const int lane = tid & 63;
  const int w = tid >> 6;
  const int lg = lane >> 4;
  const int lc = lane & 15;

  __shared__ __align__(16) short Kh[2 * 64 * 64];
  __shared__ __align__(16) short Vs[2 * 64 * 64];
  __shared__ __align__(16) short Pp[4][16 * 64];
  __shared__ float fb[4][16];

  s16x8 qfh[2], qfl[2];
  {
    int gq = min(q0 + (w << 4) + lc, NT - 1);
#pragma unroll
    for (int ks = 0; ks < 2; ++ks) {
      qfh[ks] = *(const s16x8*)(qkh + (size_t)gq * 2048 + h * 64 + ks * 32 + (lg << 3));
      qfl[ks] = *(const s16x8*)(ql + (size_t)gq * 1024 + h * 64 + ks * 32 + (lg << 3));
    }
  }

  auto issueKV = [&](int kt, int buf) {
    const int bo = buf << 12;
#pragma unroll
    for (int ii = 0; ii < 2; ++ii) {
      int r8 = (((w << 1) + ii) << 3);
      int row = r8 + (lane >> 3);
      int cg = (lane & 7) ^ (row & 7);
      int gk = min(kt * 64 + row, NT - 1);
      glds16(qkh + (size_t)gk * 2048 + 1024 + h * 64 + (cg << 3), &Kh[bo + (r8 << 6)]);
      glds16(vt + (size_t)(h * 64 + row) * VTS + kt * 64 + (cg << 3), &Vs[bo + (r8 << 6)]);
    }
  };

  float rm_r[4], rl_r[4];
#pragma unroll
  for (int r = 0; r < 4; ++r) { rm_r[r] = -3.0e38f; rl_r[r] = 0.f; }
  f32x4 o_acc[4];
  {
    f32x4 zf = {0.f, 0.f, 0.f, 0.f};
#pragma unroll
    for (int nd = 0; nd < 4; ++nd) o_acc[nd] = zf;
  }

  issueKV(0, 0);
  __syncthreads();
  issueKV(1, 1);

  for (int kt = 0; kt < NKT; ++kt) {
    const int cb = (kt & 1) << 12;

    f32x4 sc[4];
    {
      f32x4 zf = {0.f, 0.f, 0.f, 0.f};
#pragma unroll
      for (int ni = 0; ni < 4; ++ni) sc[ni] = zf;
    }
    __builtin_amdgcn_s_setprio(1);
#pragma unroll
    for (int ni = 0; ni < 4; ++ni) {
#pragma unroll
      for (int ks = 0; ks < 2; ++ks) {
        int row = (ni << 4) + lc;
        int ch = ((ks << 2) + lg) ^ (row & 7);
        s16x8 kh = *(const s16x8*)&Kh[cb + (row << 6) + (ch << 3)];
        sc[ni] = __builtin_amdgcn_mfma_f32_16x16x32_bf16(qfh[ks], kh, sc[ni], 0, 0, 0);
        sc[ni] = __builtin_amdgcn_mfma_f32_16x16x32_bf16(qfl[ks], kh, sc[ni], 0, 0, 0);
      }
    }
    __builtin_amdgcn_s_setprio(0);

    unsigned wr0[4], wr1[4];
#pragma unroll
    for (int r = 0; r < 4; ++r) {
      int gq = q0 + (w << 4) + (lg << 2) + r;
      wr0[r] = 0xFFFFFFFFu; wr1[r] = 0xFFFFFFFFu;
      if (gq < NQ) {
        wr0[r] = bits[gq * NWRD + (kt << 1)];
        wr1[r] = ((kt << 1) + 1 < NWRD) ? bits[gq * NWRD + (kt << 1) + 1] : 0u;
      }
    }
    const int kvb = kt << 6;
#pragma unroll
    for (int ni = 0; ni < 4; ++ni) {
      int kv = kvb + (ni << 4) + lc;
      unsigned bitpos = ((ni & 1) << 4) + lc;
#pragma unroll
      for (int r = 0; r < 4; ++r) {
        float sv = sc[ni][r] * 0.125f;
        unsigned wd = (ni < 2) ? wr0[r] : wr1[r];
        if (!((wd >> bitpos) & 1u)) sv -= 1e9f;
        sc[ni][r] = (kv < NT) ? sv : -3.0e38f;
      }
    }

    float fr[4];
#pragma unroll
    for (int r = 0; r < 4; ++r) {
      float tm = fmaxf(fmaxf(sc[0][r], sc[1][r]), fmaxf(sc[2][r], sc[3][r]));
#pragma unroll
      for (int m2 = 1; m2 < 16; m2 <<= 1) tm = fmaxf(tm, __shfl_xor(tm, m2, 64));
      float mnew = fmaxf(rm_r[r], tm);
      float f = __expf(rm_r[r] - mnew);
      float ps = 0.f;
#pragma unroll
      for (int ni = 0; ni < 4; ++ni) {
        float e = __expf(sc[ni][r] - mnew);
        sc[ni][r] = e;
        ps += e;
      }
#pragma unroll
      for (int m2 = 1; m2 < 16; m2 <<= 1) ps += __shfl_xor(ps, m2, 64);
      rm_r[r] = mnew;
      rl_r[r] = rl_r[r] * f + ps;
      fr[r] = f;
    }

    short* P = Pp[w];
#pragma unroll
    for (int ni = 0; ni < 4; ++ni) {
#pragma unroll
      for (int r = 0; r < 4; ++r) {
        int qq = (lg << 2) + r;
        int col = (ni << 4) + lc;
        P[(qq << 6) + (((col >> 3) ^ (qq & 7)) << 3) + (col & 7)] = f2bf(sc[ni][r]);
      }
    }
    if (lc == 0) {
#pragma unroll
      for (int r = 0; r < 4; ++r) fb[w][(lg << 2) + r] = fr[r];
    }
    float fq = fb[w][lc];
#pragma unroll
    for (int nd = 0; nd < 4; ++nd)
#pragma unroll
      for (int r = 0; r < 4; ++r) o_acc[nd][r] *= fq;

    s16x8 pfrag[2];
#pragma unroll
    for (int ks = 0; ks < 2; ++ks)
      pfrag[ks] = *(const s16x8*)&P[(lc << 6) + ((((ks << 2) + lg) ^ (lc & 7)) << 3)];
    __builtin_amdgcn_s_setprio(1);
#pragma unroll
    for (int nd = 0; nd < 4; ++nd) {
      int row = (nd << 4) + lc;
#pragma unroll
      for (int ks = 0; ks < 2; ++ks) {
        s16x8 vh = *(const s16x8*)&Vs[cb + (row << 6) + ((((ks << 2) + lg) ^ (row & 7)) << 3)];
        o_acc[nd] = __builtin_amdgcn_mfma_f32_16x16x32_bf16(vh, pfrag[ks], o_acc[nd], 0, 0, 0);
      }
    }
    __builtin_amdgcn_s_setprio(0);

    if (kt + 1 < NKT) {
      __syncthreads();
      if (kt + 2 < NKT) issueKV(kt + 2, kt & 1);
    }
  }

  if (lc == 0) {
#pragma unroll
    for (int r = 0; r < 4; ++r) fb[w][(lg << 2) + r] = rl_r[r];
  }
  float inv = 1.0f / fb[w][lc];
  int gq = q0 + (w << 4) + lc;
  if (gq < NT) {
#pragma unroll
    for (int nd = 0; nd < 4; ++nd) {
      short hh[4];
#pragma unroll
      for (int r = 0; r < 4; ++r) hh[r] = f2bf(o_acc[nd][r] * inv);
      size_t o = (size_t)gq * DM + h * 64 + (nd << 4) + (lg << 2);
      *(short4*)(ao_h + o) = make_short4(hh[0], hh[1], hh[2], hh[3]);
    }
  }
}

extern "C" void kernel_launch(void* const* d_in, const int* in_sizes, int n_in,
                              void* d_out, int out_size, void* d_ws, size_t ws_size,
                              hipStream_t stream) {
  const float* x_tokens = (const float*)d_in[0];
  const float* q_weight = (const float*)d_in[1];
  const float* norm_g   = (const float*)d_in[2];
  const float* norm_b   = (const float*)d_in[3];
  const float* class_W  = (const float*)d_in[4];
  const float* class_b  = (const float*)d_in[5];
  const float* mask_W1  = (const float*)d_in[6];
  const float* mask_b1  = (const float*)d_in[7];
  const float* mask_W2  = (const float*)d_in[8];
  const float* mask_b2  = (const float*)d_in[9];
  const float* mask_W3  = (const float*)d_in[10];
  const float* mask_b3  = (const float*)d_in[11];
  const float* ln1_g    = (const float*)d_in[12];
  const float* ln1_b    = (const float*)d_in[13];
  const float* ln2_g    = (const float*)d_in[14];
  const float* ln2_b    = (const float*)d_in[15];
  const float* qkv_W    = (const float*)d_in[16];
  const float* qkv_b    = (const float*)d_in[17];
  const float* proj_W   = (const float*)d_in[18];
  const float* proj_b   = (const float*)d_in[19];
  const float* ls1      = (const float*)d_in[20];
  const float* ls2      = (const float*)d_in[21];
  const float* fc1_W    = (const float*)d_in[22];
  const float* fc1_b    = (const float*)d_in[23];
  const float* fc2_W    = (const float*)d_in[24];
  const float* fc2_b    = (const float*)d_in[25];

  float* out = (float*)d_out;

  // ---- workspace carve (~59.0 MB, < 60.86 proven) ----
  char* p = (char*)d_ws;
  auto alloc = [&](size_t bytes) {
    char* r = p;
    p += (bytes + 255) & ~(size_t)255;
    return r;
  };
  float* x     = (float*)alloc((size_t)NT * DM * 4);        // 7.39
  short* lnb_h = (short*)alloc((size_t)NT * DM * 2);        // 3.70
  short* lnb_l = (short*)alloc((size_t)NT * DM * 2);        // 3.70
  char*  A1    = alloc((size_t)16 * DM * DM);               // 16.78 (max occupant: fc weights)
  char*  A2    = alloc((size_t)NT * 4 * DM * 2);            // 14.78
  unsigned* bias_bits = (unsigned*)alloc((size_t)NQ * NWRD * 4);
  // persistent converted mask weights (layer-invariant; 5 uses each): 12.58 MB
  short* m1Th = (short*)alloc((size_t)DM * DM * 2);
  short* m1Tl = (short*)alloc((size_t)DM * DM * 2);
  short* m2Th = (short*)alloc((size_t)DM * DM * 2);
  short* m2Tl = (short*)alloc((size_t)DM * DM * 2);
  short* m3Th = (short*)alloc((size_t)DM * DM * 2);
  short* m3Tl = (short*)alloc((size_t)DM * DM * 2);

  // A1 occupants (time-multiplexed):
  short* qkvh  = (short*)A1;                         // [NT][2048] Q|K hi (7.39)
  short* qkvl  = qkvh + (size_t)NT * 2048;           // [NT][1024] Q lo (3.70)
  short* vtb   = qkvl + (size_t)NT * 1024;           // [1024][VTS] V^T hi (3.80)
  short* fTh   = (short*)A1;                         // fc1/fc2 cvt weights (after fattn)
  short* fTl   = fTh + (size_t)4 * DM * DM;          // ends at 16.78 exactly
  short* f1_h = (short*)A1;                          // predict scratch (first 2.46 MB)
  short* f1_l = f1_h + (size_t)NQ * DM;
  short* f2_h = f1_l + (size_t)NQ * DM;
  short* f2_l = f2_h + (size_t)NQ * DM;
  short* f3_h = f2_l + (size_t)NQ * DM;
  short* f3_l = f3_h + (size_t)NQ * DM;
  float* pbuf = (float*)(A1 + ((size_t)4 << 20));    // predict partials at A1+4MB (<=6.55MB)
  // A2 occupants (time-multiplexed):
  short* qTh   = (short*)A2;                         // qkv cvt weights (before fattn)
  short* qTl   = qTh + (size_t)3 * DM * DM;
  short* aoh   = (short*)A2;                         // fattn out hi (first 3.70 MB)
  short* pTh   = (short*)(A2 + (size_t)NT * DM * 4); // proj cvt weights (upper half)
  short* pTl   = pTh + (size_t)DM * DM;
  short* g1h   = (short*)A2;                         // fc1 out (full; after proj)

  const int ELEM_GRID = (NT * DM + 255) / 256;
  auto g128 = [](int M, int Nc, int ks) { return dim3((Nc + 127) / 128, (M + 127) / 128, ks); };
  auto g64  = [](int M, int Nc, int ks) { return dim3((Nc + 127) / 128, (M + 63) / 64, ks); };
  auto rgrid = [](int n) { return dim3((n + 255) / 256); };
  auto cgrid = [](int K, int N) { return dim3(N / 32, K / 32); };

  // one-time per launch: convert layer-invariant predict weights (5 uses each)
  cvtT_kernel<<<cgrid(DM, DM), 256, 0, stream>>>(mask_W1, m1Th, m1Tl, DM, DM);
  cvtT_kernel<<<cgrid(DM, DM), 256, 0, stream>>>(mask_W2, m2Th, m2Tl, DM, DM);
  cvtT_kernel<<<cgrid(DM, DM), 256, 0, stream>>>(mask_W3, m3Th, m3Tl, DM, DM);
  concat_kernel<<<ELEM_GRID, 256, 0, stream>>>(q_weight, x_tokens, x);

  for (int i = 0; i <= NBLK; ++i) {
    // ---- predict head on shared-norm LN(x) (full 3-term; protects mask sign test) ----
    ln_kernel<<<NT, 256, 0, stream>>>(x, norm_g, norm_b, lnb_h, lnb_l);
    float* mask_i = out + (size_t)i * NQ * NPATCH;
    float* cls_i  = out + (size_t)5 * NQ * NPATCH + (size_t)i * NQ * NCLS;
    mgemm_kernel<1, 1, 1, 0, 3, 8><<<g64(NQ, DM, 8), 256, 0, stream>>>(
        lnb_h, lnb_l, nullptr, m1Th, m1Tl, mask_b1, nullptr, pbuf, nullptr, nullptr, NQ, DM, DM);
    redsplit_kernel<1, 1><<<rgrid(NQ * DM), 256, 0, stream>>>(pbuf, nullptr, f1_h, f1_l, 8, NQ * DM);
    mgemm_kernel<1, 1, 1, 0, 3, 8><<<g64(NQ, DM, 8), 256, 0, stream>>>(
        f1_h, f1_l, nullptr, m2Th, m2Tl, mask_b2, nullptr, pbuf, nullptr, nullptr, NQ, DM, DM);
    redsplit_kernel<1, 1><<<rgrid(NQ * DM), 256, 0, stream>>>(pbuf, nullptr, f2_h, f2_l, 8, NQ * DM);
    mgemm_kernel<1, 1, 1, 0, 3, 8><<<g64(NQ, DM, 8), 256, 0, stream>>>(
        f2_h, f2_l, nullptr, m3Th, m3Tl, mask_b3, nullptr, pbuf, nullptr, nullptr, NQ, DM, DM);
    redsplit_kernel<0, 1><<<rgrid(NQ * DM), 256, 0, stream>>>(pbuf, nullptr, f3_h, f3_l, 8, NQ * DM);
    mgemm_kernel<1, 1, 1, 0, 3, 4><<<g64(NQ, NPATCH, 4), 256, 0, stream>>>(
        f3_h, f3_l, nullptr, lnb_h + (size_t)(NQ + PFX) * DM, lnb_l + (size_t)(NQ + PFX) * DM,
        nullptr, nullptr, pbuf, nullptr, nullptr, NQ, NPATCH, DM);
    redsplit_kernel<0, 0><<<rgrid(NQ * NPATCH), 256, 0, stream>>>(
        pbuf, mask_i, nullptr, nullptr, 4, NQ * NPATCH);
    mgemm_kernel<1, 0, 1, 0, 3, 8><<<g64(NQ, NCLS, 8), 256, 0, stream>>>(
        lnb_h, lnb_l, class_W, nullptr, nullptr, class_b, nullptr, pbuf, nullptr, nullptr, NQ, NCLS, DM);
    redsplit_kernel<0, 0><<<rgrid(NQ * NCLS), 256, 0, stream>>>(
        pbuf, cls_i, nullptr, nullptr, 8, NQ * NCLS);
    if (i == NBLK) break;

    // ---- transformer block i ----
    ln_kernel<<<NT, 256, 0, stream>>>(x, ln1_g + i * DM, ln1_b + i * DM, lnb_h, lnb_l);
    cvtT_kernel<<<cgrid(DM, 3 * DM), 256, 0, stream>>>(
        qkv_W + (size_t)i * DM * 3 * DM, qTh, qTl, DM, 3 * DM);
    mgemm_kernel<0, 1, 0, 0, 7, 1><<<g128(NT, 3 * DM, 1), 256, 0, stream>>>(
        lnb_h, lnb_l, nullptr, qTh, qTl, qkv_b + i * 3 * DM, nullptr,
        (float*)vtb, qkvh, qkvl, NT, 3 * DM, DM);
    maskpack_kernel<<<(NQ * NWRD + 255) / 256, 256, 0, stream>>>(mask_i, bias_bits);
    fattn_kernel<<<NKT * NHEAD, 256, 0, stream>>>(qkvh, qkvl, vtb, bias_bits, aoh);
    cvtT_kernel<<<cgrid(DM, DM), 256, 0, stream>>>(
        proj_W + (size_t)i * DM * DM, pTh, pTl, DM, DM);
    mgemm_kernel<1, 1, 0, 0, 5, 4><<<g64(NT, DM, 4), 256, 0, stream>>>(
        aoh, nullptr, nullptr, pTh, pTl, proj_b + i * DM, ls1 + i * DM,
        x, nullptr, nullptr, NT, DM, DM);
    ln_kernel<<<NT, 256, 0, stream>>>(x, ln2_g + i * DM, ln2_b + i * DM, lnb_h, lnb_l);
    cvtT_kernel<<<cgrid(DM, 4 * DM), 256, 0, stream>>>(
        fc1_W + (size_t)i * DM * 4 * DM, fTh, fTl, DM, 4 * DM);
    mgemm_kernel<0, 1, 0, 1, 4, 1><<<g128(NT, 4 * DM, 1), 256, 0, stream>>>(
        lnb_h, lnb_l, nullptr, fTh, fTl, fc1_b + i * 4 * DM, nullptr,
        nullptr, g1h, nullptr, NT, 4 * DM, DM);
    cvtT_kernel<<<cgrid(4 * DM, DM), 256, 0, stream>>>(
        fc2_W + (size_t)i * 4 * DM * DM, fTh, fTl, 4 * DM, DM);
    mgemm_kernel<1, 1, 0, 0, 5, 4><<<g64(NT, DM, 4), 256, 0, stream>>>(
        g1h, nullptr, nullptr, fTh, fTl, fc2_b + i * DM, ls2 + i * DM,
        x, nullptr, nullptr, NT, DM, 4 * DM);
  }
}

// Round 21
// 1378.628 us; speedup vs baseline: 1.1247x; 1.1247x over previous
//
#include <hip/hip_runtime.h>
#include <hip/hip_bf16.h>

#define NQ 200
#define PFX 5
#define NPATCH 1600
#define NT 1805
#define DM 1024
#define NHEAD 16
#define DHEAD 64
#define NBLK 4
#define NCLS 151
#define NKT 29     // ceil(1805/64) kv tiles
#define NWRD 57    // ceil(1805/32) mask words per query row
#define VTS 1856   // V^T row stride (NKT*64, 16B-aligned)

typedef short s16x8 __attribute__((ext_vector_type(8)));
typedef float f32x4 __attribute__((ext_vector_type(4)));

__device__ __forceinline__ float gelu_f(float x) {
  return 0.5f * x * (1.0f + erff(x * 0.7071067811865476f));
}
__device__ __forceinline__ short f2bf(float x) {
  __hip_bfloat16 h = __float2bfloat16(x);
  return *reinterpret_cast<short*>(&h);
}
__device__ __forceinline__ float bf2f(short s) {
  __hip_bfloat16 h;
  *reinterpret_cast<short*>(&h) = s;
  return __bfloat162float(h);
}
// async 16B global->LDS (width literal 16). LDS dest wave-uniform base + lane*16B.
__device__ __forceinline__ void glds16(const void* g, void* l) {
  __builtin_amdgcn_global_load_lds(
      (const __attribute__((address_space(1))) void*)g,
      (__attribute__((address_space(3))) void*)l, 16, 0, 0);
}

// ---------------- concat: x = [q_weight ; x_tokens] ----------------
__global__ __launch_bounds__(256) void concat_kernel(const float* __restrict__ qw,
    const float* __restrict__ xt, float* __restrict__ x) {
  int idx = blockIdx.x * 256 + threadIdx.x;
  if (idx >= NT * DM) return;
  int n = idx >> 10;
  x[idx] = (n < NQ) ? qw[idx] : xt[idx - NQ * DM];
}

// ---------------- weight transpose+split: W (K x N fp32) -> Th (+Tl if WRL) ----------------
template <int WRL>
__global__ __launch_bounds__(256) void cvtT_kernel(const float* __restrict__ W,
    short* __restrict__ Th, short* __restrict__ Tl, int K, int N) {
  __shared__ float t[32][33];
  const int n0 = blockIdx.x * 32, k0 = blockIdx.y * 32;
  const int tx = threadIdx.x & 31, ty = threadIdx.x >> 5;
#pragma unroll
  for (int i = 0; i < 32; i += 8)
    t[ty + i][tx] = W[(size_t)(k0 + ty + i) * N + n0 + tx];
  __syncthreads();
#pragma unroll
  for (int i = 0; i < 32; i += 8) {
    int n = n0 + ty + i, k = k0 + tx;
    float xv = t[tx][ty + i];
    short hh = f2bf(xv);
    Th[(size_t)n * K + k] = hh;
    if (WRL) Tl[(size_t)n * K + k] = f2bf(xv - bf2f(hh));
  }
}

// ---------------- LayerNorm -> bf16 hi/lo ----------------
__global__ __launch_bounds__(256) void ln_kernel(const float* __restrict__ in,
    const float* __restrict__ g, const float* __restrict__ b,
    short* __restrict__ oh, short* __restrict__ ol) {
  const int row = blockIdx.x;
  const int tid = threadIdx.x;
  const float* x = in + (size_t)row * DM;
  float v[4];
#pragma unroll
  for (int i = 0; i < 4; ++i) v[i] = x[tid + (i << 8)];
  float s = v[0] + v[1] + v[2] + v[3];
  __shared__ float red[4];
  __shared__ float red2[4];
#pragma unroll
  for (int off = 32; off; off >>= 1) s += __shfl_down(s, off, 64);
  if ((tid & 63) == 0) red[tid >> 6] = s;
  __syncthreads();
  float mean = (red[0] + red[1] + red[2] + red[3]) * (1.0f / DM);
  float sq = 0.f;
#pragma unroll
  for (int i = 0; i < 4; ++i) { float d = v[i] - mean; sq += d * d; }
#pragma unroll
  for (int off = 32; off; off >>= 1) sq += __shfl_down(sq, off, 64);
  if ((tid & 63) == 0) red2[tid >> 6] = sq;
  __syncthreads();
  float var = (red2[0] + red2[1] + red2[2] + red2[3]) * (1.0f / DM);
  float inv = 1.0f / sqrtf(var + 1e-6f);
#pragma unroll
  for (int i = 0; i < 4; ++i) {
    int d = tid + (i << 8);
    float y = (v[i] - mean) * inv * g[d] + b[d];
    short hh = f2bf(y);
    oh[(size_t)row * DM + d] = hh;
    ol[(size_t)row * DM + d] = f2bf(y - bf2f(hh));
  }
}

// ---------------- bf16 MFMA GEMM: dbuf LDS + split-K + fused epilogues ----------------
// Terms: Ah·Bh always; +Ah·Bl if BLO; +Al·Bh if ALO.
// OMODE: 0 bf16 h/l out (+ACT); 1 fp32 out (+ACT); 2 atomicAdd fp32 (bias z==0);
//        3 partial fp32 at Cf + z*M*N (bias z==0);
//        4 bf16 HI-only out (+ACT);
//        5 fused residual: atomicAdd(Cf[o], lsv[col]*(v+bias)) (bias z==0);
//        7 qkv layout: Q->Ch[row][2048]+Cl[row][1024], K->Ch hi, V->V^T[(col-2048)][row]
//          (V^T buffer passed via Cf, stride VTS).
template <int BM64, int BSRC, int ALO, int BLO, int ACT, int OMODE, int KS>
__global__ __launch_bounds__(256) void mgemm_kernel(
    const short* __restrict__ Ah, const short* __restrict__ Al,
    const float* __restrict__ Wf,
    const short* __restrict__ Bh, const short* __restrict__ Bl,
    const float* __restrict__ bias, const float* __restrict__ lsv,
    float* __restrict__ Cf, short* __restrict__ Ch, short* __restrict__ Cl,
    int M, int N, int K) {
  constexpr int BM = BM64 ? 64 : 128;
  constexpr int AT = BM64 ? 2 : 4;
  constexpr int AISS = BM64 ? 1 : 2;
  __shared__ __align__(16) short sAh[2 * BM * 32];
  __shared__ __align__(16) short sAl[ALO ? 2 * BM * 32 : 8];
  __shared__ __align__(16) short sBh[2 * 128 * 32];
  __shared__ __align__(16) short sBl[BLO ? 2 * 128 * 32 : 8];
  const int tid = threadIdx.x;
  const int lane = tid & 63;
  const int w = tid >> 6;
  const int bm = blockIdx.y * BM;
  const int bn = blockIdx.x << 7;
  const int z = (KS > 1) ? blockIdx.z : 0;
  const int KL = K / KS;
  const int kbase = z * KL;

  f32x4 acc[AT][4];
  {
    f32x4 zf = {0.f, 0.f, 0.f, 0.f};
#pragma unroll
    for (int mi = 0; mi < AT; ++mi)
#pragma unroll
      for (int ni = 0; ni < 4; ++ni) acc[mi][ni] = zf;
  }

  auto issueA = [&](int buf, int k0) {
#pragma unroll
    for (int i = 0; i < AISS; ++i) {
      int br = (BM64 ? (w << 4) : (w << 5) + (i << 4));
      int r = br + (lane >> 2);
      int cg = (lane & 3) ^ ((r >> 1) & 3);
      size_t go = (size_t)min(bm + r, M - 1) * K + kbase + k0 + (cg << 3);
      glds16(Ah + go, &sAh[(buf * BM + br) * 32]);
      if (ALO) glds16(Al + go, &sAl[(buf * BM + br) * 32]);
    }
  };
  auto issueB1 = [&](int buf, int k0) {
#pragma unroll
    for (int i = 0; i < 2; ++i) {
      int br = (w << 5) + (i << 4);
      int r = br + (lane >> 2);
      int cg = (lane & 3) ^ ((r >> 1) & 3);
      size_t go = (size_t)min(bn + r, N - 1) * K + kbase + k0 + (cg << 3);
      glds16(Bh + go, &sBh[(buf * 128 + br) * 32]);
      if (BLO) glds16(Bl + go, &sBl[(buf * 128 + br) * 32]);
    }
  };
  float wv[2][8];
  auto loadB0 = [&](int k0) {
#pragma unroll
    for (int p = 0; p < 2; ++p) {
      int n = tid & 127;
      int c8 = (tid >> 7) + (p << 1);
      const float* Wp = Wf + (size_t)(kbase + k0 + (c8 << 3)) * N + min(bn + n, N - 1);
#pragma unroll
      for (int j = 0; j < 8; ++j) wv[p][j] = Wp[(size_t)j * N];
    }
  };
  auto writeB0 = [&](int buf) {
#pragma unroll
    for (int p = 0; p < 2; ++p) {
      int n = tid & 127;
      int c8 = (tid >> 7) + (p << 1);
      int cp = c8 ^ ((n >> 1) & 3);
      union { uint4 u; short e[8]; } H, L;
#pragma unroll
      for (int j = 0; j < 8; ++j) {
        short hh = f2bf(wv[p][j]);
        H.e[j] = hh;
        L.e[j] = f2bf(wv[p][j] - bf2f(hh));
      }
      int off = (buf * 128 + n) * 32 + (cp << 3);
      *(uint4*)&sBh[off] = H.u;
      if (BLO) *(uint4*)&sBl[off] = L.u;
    }
  };

  issueA(0, 0);
  if (BSRC == 1) issueB1(0, 0);
  else { loadB0(0); writeB0(0); }
  __syncthreads();

  const int nt = KL >> 5;
  int cur = 0;
  const int ar = lane & 15;
  const int kc = lane >> 4;
  const int wmr = BM64 ? ((w >> 1) << 5) : ((w >> 1) << 6);
  const int wnr = (w & 1) << 6;

  for (int t = 0; t < nt; ++t) {
    const bool more = (t + 1 < nt);
    if (more) {
      int k0n = (t + 1) << 5;
      issueA(cur ^ 1, k0n);
      if (BSRC == 1) issueB1(cur ^ 1, k0n);
      else loadB0(k0n);
    }
    s16x8 fah[AT], fal[AT], fbh[4], fbl[4];
#pragma unroll
    for (int t2 = 0; t2 < AT; ++t2) {
      int r = wmr + (t2 << 4) + ar;
      int off = (cur * BM + r) * 32 + ((kc ^ ((r >> 1) & 3)) << 3);
      fah[t2] = *(const s16x8*)&sAh[off];
      if (ALO) fal[t2] = *(const s16x8*)&sAl[off];
    }
#pragma unroll
    for (int t2 = 0; t2 < 4; ++t2) {
      int r = wnr + (t2 << 4) + ar;
      int off = (cur * 128 + r) * 32 + ((kc ^ ((r >> 1) & 3)) << 3);
      fbh[t2] = *(const s16x8*)&sBh[off];
      if (BLO) fbl[t2] = *(const s16x8*)&sBl[off];
    }
#pragma unroll
    for (int mi = 0; mi < AT; ++mi)
#pragma unroll
      for (int ni = 0; ni < 4; ++ni) {
        acc[mi][ni] = __builtin_amdgcn_mfma_f32_16x16x32_bf16(fah[mi], fbh[ni], acc[mi][ni], 0, 0, 0);
        if (BLO)
          acc[mi][ni] = __builtin_amdgcn_mfma_f32_16x16x32_bf16(fah[mi], fbl[ni], acc[mi][ni], 0, 0, 0);
        if (ALO)
          acc[mi][ni] = __builtin_amdgcn_mfma_f32_16x16x32_bf16(fal[mi], fbh[ni], acc[mi][ni], 0, 0, 0);
      }
    if (more) {
      if (BSRC == 0) writeB0(cur ^ 1);
      __syncthreads();
      cur ^= 1;
    }
  }

  const int erow = bm + wmr + ((lane >> 4) << 2);
  const int ecol = bn + wnr + (lane & 15);
  float bv[4], lv[4];
#pragma unroll
  for (int ni = 0; ni < 4; ++ni) {
    int col = ecol + ni * 16;
    float b0 = (bias != nullptr && col < N) ? bias[col] : 0.f;
    bv[ni] = (KS > 1 && z != 0) ? 0.f : b0;
    lv[ni] = (OMODE == 5 && col < N) ? lsv[col] : 0.f;
  }
#pragma unroll
  for (int mi = 0; mi < AT; ++mi) {
#pragma unroll
    for (int rr = 0; rr < 4; ++rr) {
      int row = erow + mi * 16 + rr;
      if (row >= M) continue;
#pragma unroll
      for (int ni = 0; ni < 4; ++ni) {
        int col = ecol + ni * 16;
        if (col >= N) continue;
        float v = acc[mi][ni][rr] + bv[ni];
        size_t o = (size_t)row * N + col;
        if (OMODE == 0) {
          if (ACT == 1) v = gelu_f(v);
          short hh = f2bf(v);
          Ch[o] = hh;
          Cl[o] = f2bf(v - bf2f(hh));
        } else if (OMODE == 1) {
          if (ACT == 1) v = gelu_f(v);
          Cf[o] = v;
        } else if (OMODE == 2) {
          atomicAdd(&Cf[o], v);
        } else if (OMODE == 3) {
          Cf[(size_t)z * M * N + o] = v;
        } else if (OMODE == 4) {
          if (ACT == 1) v = gelu_f(v);
          Ch[o] = f2bf(v);
        } else if (OMODE == 5) {
          atomicAdd(&Cf[o], lv[ni] * v);
        } else {  // OMODE == 7: qkv split layout + V^T emission
          short hh = f2bf(v);
          if (col < 1024) {
            Ch[(size_t)row * 2048 + col] = hh;
            Cl[(size_t)row * 1024 + col] = f2bf(v - bf2f(hh));
          } else if (col < 2048) {
            Ch[(size_t)row * 2048 + col] = hh;
          } else {
            ((short*)Cf)[(size_t)(col - 2048) * VTS + row] = hh;
          }
        }
      }
    }
  }
}

// ---------------- split-K partial reduce (+act, +bf16 hi/lo split) ----------------
template <int ACT, int WSPLIT>
__global__ __launch_bounds__(256) void redsplit_kernel(const float* __restrict__ pb,
    float* __restrict__ outf, short* __restrict__ oh, short* __restrict__ ol,
    int KSr, int MN) {
  int idx = blockIdx.x * 256 + threadIdx.x;
  if (idx >= MN) return;
  float s = 0.f;
  for (int zz = 0; zz < KSr; ++zz) s += pb[(size_t)zz * MN + idx];
  if (ACT == 1) s = gelu_f(s);
  if (WSPLIT) {
    short hh = f2bf(s);
    oh[idx] = hh;
    ol[idx] = f2bf(s - bf2f(hh));
  } else {
    outf[idx] = s;
  }
}

// ---------------- pack attention keep-mask into bits ----------------
__global__ __launch_bounds__(256) void maskpack_kernel(const float* __restrict__ mlog,
    unsigned* __restrict__ bits) {
  int idx = blockIdx.x * 256 + threadIdx.x;
  if (idx >= NQ * NWRD) return;
  int q = idx / NWRD, w = idx - q * NWRD;
  unsigned word = 0u;
  int c0 = w * 32;
#pragma unroll
  for (int b = 0; b < 32; ++b) {
    int c = c0 + b;
    unsigned keep;
    if (c < NQ + PFX) keep = 1u;
    else if (c < NT) keep = (mlog[(size_t)q * NPATCH + (c - NQ - PFX)] > 0.f) ? 1u : 0u;
    else keep = 0u;
    word |= keep << b;
  }
  bits[idx] = word;
}

// ---------------- flash attention: glds16-staged K & pre-transposed V ----------------
// qkh: [NT][2048] Q|K hi. ql: [NT][1024] Q lo. vt: [1024][VTS] V^T hi.
// S = (Qh+Ql)·Kh; PV 1-term. One barrier/tile; tile t+2 issued after barrier of t.
__global__ __launch_bounds__(256, 2) void fattn_kernel(
    const short* __restrict__ qkh, const short* __restrict__ ql,
    const short* __restrict__ vt, const unsigned* __restrict__ bits,
    short* __restrict__ ao_h) {
  const int bid = blockIdx.x;
  const int h = bid & 15;
  const int q0 = (bid >> 4) * 64;
  const int tid = threadIdx.x;
  const int lane = tid & 63;
  const int w = tid >> 6;
  const int lg = lane >> 4;
  const int lc = lane & 15;

  __shared__ __align__(16) short Kh[2 * 64 * 64];
  __shared__ __align__(16) short Vs[2 * 64 * 64];
  __shared__ __align__(16) short Pp[4][16 * 64];
  __shared__ float fb[4][16];

  s16x8 qfh[2], qfl[2];
  {
    int gq = min(q0 + (w << 4) + lc, NT - 1);
#pragma unroll
    for (int ks = 0; ks < 2; ++ks) {
      qfh[ks] = *(const s16x8*)(qkh + (size_t)gq * 2048 + h * 64 + ks * 32 + (lg << 3));
      qfl[ks] = *(const s16x8*)(ql + (size_t)gq * 1024 + h * 64 + ks * 32 + (lg << 3));
    }
  }

  auto issueKV = [&](int kt, int buf) {
    const int bo = buf << 12;
#pragma unroll
    for (int ii = 0; ii < 2; ++ii) {
      int r8 = (((w << 1) + ii) << 3);
      int row = r8 + (lane >> 3);
      int cg = (lane & 7) ^ (row & 7);
      int gk = min(kt * 64 + row, NT - 1);
      glds16(qkh + (size_t)gk * 2048 + 1024 + h * 64 + (cg << 3), &Kh[bo + (r8 << 6)]);
      glds16(vt + (size_t)(h * 64 + row) * VTS + kt * 64 + (cg << 3), &Vs[bo + (r8 << 6)]);
    }
  };

  float rm_r[4], rl_r[4];
#pragma unroll
  for (int r = 0; r < 4; ++r) { rm_r[r] = -3.0e38f; rl_r[r] = 0.f; }
  f32x4 o_acc[4];
  {
    f32x4 zf = {0.f, 0.f, 0.f, 0.f};
#pragma unroll
    for (int nd = 0; nd < 4; ++nd) o_acc[nd] = zf;
  }

  issueKV(0, 0);
  __syncthreads();
  issueKV(1, 1);

  for (int kt = 0; kt < NKT; ++kt) {
    const int cb = (kt & 1) << 12;

    f32x4 sc[4];
    {
      f32x4 zf = {0.f, 0.f, 0.f, 0.f};
#pragma unroll
      for (int ni = 0; ni < 4; ++ni) sc[ni] = zf;
    }
    __builtin_amdgcn_s_setprio(1);
#pragma unroll
    for (int ni = 0; ni < 4; ++ni) {
#pragma unroll
      for (int ks = 0; ks < 2; ++ks) {
        int row = (ni << 4) + lc;
        int ch = ((ks << 2) + lg) ^ (row & 7);
        s16x8 kh = *(const s16x8*)&Kh[cb + (row << 6) + (ch << 3)];
        sc[ni] = __builtin_amdgcn_mfma_f32_16x16x32_bf16(qfh[ks], kh, sc[ni], 0, 0, 0);
        sc[ni] = __builtin_amdgcn_mfma_f32_16x16x32_bf16(qfl[ks], kh, sc[ni], 0, 0, 0);
      }
    }
    __builtin_amdgcn_s_setprio(0);

    unsigned wr0[4], wr1[4];
#pragma unroll
    for (int r = 0; r < 4; ++r) {
      int gq = q0 + (w << 4) + (lg << 2) + r;
      wr0[r] = 0xFFFFFFFFu; wr1[r] = 0xFFFFFFFFu;
      if (gq < NQ) {
        wr0[r] = bits[gq * NWRD + (kt << 1)];
        wr1[r] = ((kt << 1) + 1 < NWRD) ? bits[gq * NWRD + (kt << 1) + 1] : 0u;
      }
    }
    const int kvb = kt << 6;
#pragma unroll
    for (int ni = 0; ni < 4; ++ni) {
      int kv = kvb + (ni << 4) + lc;
      unsigned bitpos = ((ni & 1) << 4) + lc;
#pragma unroll
      for (int r = 0; r < 4; ++r) {
        float sv = sc[ni][r] * 0.125f;
        unsigned wd = (ni < 2) ? wr0[r] : wr1[r];
        if (!((wd >> bitpos) & 1u)) sv -= 1e9f;
        sc[ni][r] = (kv < NT) ? sv : -3.0e38f;
      }
    }

    float fr[4];
#pragma unroll
    for (int r = 0; r < 4; ++r) {
      float tm = fmaxf(fmaxf(sc[0][r], sc[1][r]), fmaxf(sc[2][r], sc[3][r]));
#pragma unroll
      for (int m2 = 1; m2 < 16; m2 <<= 1) tm = fmaxf(tm, __shfl_xor(tm, m2, 64));
      float mnew = fmaxf(rm_r[r], tm);
      float f = __expf(rm_r[r] - mnew);
      float ps = 0.f;
#pragma unroll
      for (int ni = 0; ni < 4; ++ni) {
        float e = __expf(sc[ni][r] - mnew);
        sc[ni][r] = e;
        ps += e;
      }
#pragma unroll
      for (int m2 = 1; m2 < 16; m2 <<= 1) ps += __shfl_xor(ps, m2, 64);
      rm_r[r] = mnew;
      rl_r[r] = rl_r[r] * f + ps;
      fr[r] = f;
    }

    short* P = Pp[w];
#pragma unroll
    for (int ni = 0; ni < 4; ++ni) {
#pragma unroll
      for (int r = 0; r < 4; ++r) {
        int qq = (lg << 2) + r;
        int col = (ni << 4) + lc;
        P[(qq << 6) + (((col >> 3) ^ (qq & 7)) << 3) + (col & 7)] = f2bf(sc[ni][r]);
      }
    }
    if (lc == 0) {
#pragma unroll
      for (int r = 0; r < 4; ++r) fb[w][(lg << 2) + r] = fr[r];
    }
    float fq = fb[w][lc];
#pragma unroll
    for (int nd = 0; nd < 4; ++nd)
#pragma unroll
      for (int r = 0; r < 4; ++r) o_acc[nd][r] *= fq;

    s16x8 pfrag[2];
#pragma unroll
    for (int ks = 0; ks < 2; ++ks)
      pfrag[ks] = *(const s16x8*)&P[(lc << 6) + ((((ks << 2) + lg) ^ (lc & 7)) << 3)];
    __builtin_amdgcn_s_setprio(1);
#pragma unroll
    for (int nd = 0; nd < 4; ++nd) {
      int row = (nd << 4) + lc;
#pragma unroll
      for (int ks = 0; ks < 2; ++ks) {
        s16x8 vh = *(const s16x8*)&Vs[cb + (row << 6) + ((((ks << 2) + lg) ^ (row & 7)) << 3)];
        o_acc[nd] = __builtin_amdgcn_mfma_f32_16x16x32_bf16(vh, pfrag[ks], o_acc[nd], 0, 0, 0);
      }
    }
    __builtin_amdgcn_s_setprio(0);

    if (kt + 1 < NKT) {
      __syncthreads();
      if (kt + 2 < NKT) issueKV(kt + 2, kt & 1);
    }
  }

  if (lc == 0) {
#pragma unroll
    for (int r = 0; r < 4; ++r) fb[w][(lg << 2) + r] = rl_r[r];
  }
  float inv = 1.0f / fb[w][lc];
  int gq = q0 + (w << 4) + lc;
  if (gq < NT) {
#pragma unroll
    for (int nd = 0; nd < 4; ++nd) {
      short hh[4];
#pragma unroll
      for (int r = 0; r < 4; ++r) hh[r] = f2bf(o_acc[nd][r] * inv);
      size_t o = (size_t)gq * DM + h * 64 + (nd << 4) + (lg << 2);
      *(short4*)(ao_h + o) = make_short4(hh[0], hh[1], hh[2], hh[3]);
    }
  }
}

extern "C" void kernel_launch(void* const* d_in, const int* in_sizes, int n_in,
                              void* d_out, int out_size, void* d_ws, size_t ws_size,
                              hipStream_t stream) {
  const float* x_tokens = (const float*)d_in[0];
  const float* q_weight = (const float*)d_in[1];
  const float* norm_g   = (const float*)d_in[2];
  const float* norm_b   = (const float*)d_in[3];
  const float* class_W  = (const float*)d_in[4];
  const float* class_b  = (const float*)d_in[5];
  const float* mask_W1  = (const float*)d_in[6];
  const float* mask_b1  = (const float*)d_in[7];
  const float* mask_W2  = (const float*)d_in[8];
  const float* mask_b2  = (const float*)d_in[9];
  const float* mask_W3  = (const float*)d_in[10];
  const float* mask_b3  = (const float*)d_in[11];
  const float* ln1_g    = (const float*)d_in[12];
  const float* ln1_b    = (const float*)d_in[13];
  const float* ln2_g    = (const float*)d_in[14];
  const float* ln2_b    = (const float*)d_in[15];
  const float* qkv_W    = (const float*)d_in[16];
  const float* qkv_b    = (const float*)d_in[17];
  const float* proj_W   = (const float*)d_in[18];
  const float* proj_b   = (const float*)d_in[19];
  const float* ls1      = (const float*)d_in[20];
  const float* ls2      = (const float*)d_in[21];
  const float* fc1_W    = (const float*)d_in[22];
  const float* fc1_b    = (const float*)d_in[23];
  const float* fc2_W    = (const float*)d_in[24];
  const float* fc2_b    = (const float*)d_in[25];

  float* out = (float*)d_out;

  // ---- workspace carve (~59.0 MB, < 60.86 proven) ----
  char* p = (char*)d_ws;
  auto alloc = [&](size_t bytes) {
    char* r = p;
    p += (bytes + 255) & ~(size_t)255;
    return r;
  };
  float* x     = (float*)alloc((size_t)NT * DM * 4);        // 7.39
  short* lnb_h = (short*)alloc((size_t)NT * DM * 2);        // 3.70
  short* lnb_l = (short*)alloc((size_t)NT * DM * 2);        // 3.70
  char*  A1    = alloc((size_t)16 * DM * DM);               // 16.78
  char*  A2    = alloc((size_t)NT * 4 * DM * 2);            // 14.78
  unsigned* bias_bits = (unsigned*)alloc((size_t)NQ * NWRD * 4);
  short* m1Th = (short*)alloc((size_t)DM * DM * 2);
  short* m1Tl = (short*)alloc((size_t)DM * DM * 2);
  short* m2Th = (short*)alloc((size_t)DM * DM * 2);
  short* m2Tl = (short*)alloc((size_t)DM * DM * 2);
  short* m3Th = (short*)alloc((size_t)DM * DM * 2);
  short* m3Tl = (short*)alloc((size_t)DM * DM * 2);

  // A1 occupants (time-multiplexed):
  short* qkvh  = (short*)A1;                         // [NT][2048] Q|K hi
  short* qkvl  = qkvh + (size_t)NT * 2048;           // [NT][1024] Q lo
  short* vtb   = qkvl + (size_t)NT * 1024;           // [1024][VTS] V^T hi
  short* fTh   = (short*)A1;                         // fc1/fc2 cvt weights (hi only used)
  short* fTl   = fTh + (size_t)4 * DM * DM;
  short* f1_h = (short*)A1;                          // predict scratch
  short* f1_l = f1_h + (size_t)NQ * DM;
  short* f2_h = f1_l + (size_t)NQ * DM;
  short* f2_l = f2_h + (size_t)NQ * DM;
  short* f3_h = f2_l + (size_t)NQ * DM;
  short* f3_l = f3_h + (size_t)NQ * DM;
  float* pbuf = (float*)(A1 + ((size_t)4 << 20));
  // A2 occupants (time-multiplexed):
  short* qTh   = (short*)A2;                         // qkv cvt weights hi
  short* qTl   = qTh + (size_t)3 * DM * DM;          // (unused w/ BLO=0; kept for layout)
  short* aoh   = (short*)A2;                         // fattn out hi
  short* pTh   = (short*)(A2 + (size_t)NT * DM * 4); // proj cvt weights hi
  short* pTl   = pTh + (size_t)DM * DM;
  short* g1h   = (short*)A2;                         // fc1 out

  const int ELEM_GRID = (NT * DM + 255) / 256;
  auto g128 = [](int M, int Nc, int ks) { return dim3((Nc + 127) / 128, (M + 127) / 128, ks); };
  auto g64  = [](int M, int Nc, int ks) { return dim3((Nc + 127) / 128, (M + 63) / 64, ks); };
  auto rgrid = [](int n) { return dim3((n + 255) / 256); };
  auto cgrid = [](int K, int N) { return dim3(N / 32, K / 32); };

  cvtT_kernel<1><<<cgrid(DM, DM), 256, 0, stream>>>(mask_W1, m1Th, m1Tl, DM, DM);
  cvtT_kernel<1><<<cgrid(DM, DM), 256, 0, stream>>>(mask_W2, m2Th, m2Tl, DM, DM);
  cvtT_kernel<1><<<cgrid(DM, DM), 256, 0, stream>>>(mask_W3, m3Th, m3Tl, DM, DM);
  concat_kernel<<<ELEM_GRID, 256, 0, stream>>>(q_weight, x_tokens, x);

  for (int i = 0; i <= NBLK; ++i) {
    // ---- predict head on shared-norm LN(x) (full 3-term; protects mask sign test) ----
    ln_kernel<<<NT, 256, 0, stream>>>(x, norm_g, norm_b, lnb_h, lnb_l);
    float* mask_i = out + (size_t)i * NQ * NPATCH;
    float* cls_i  = out + (size_t)5 * NQ * NPATCH + (size_t)i * NQ * NCLS;
    mgemm_kernel<1, 1, 1, 1, 0, 3, 8><<<g64(NQ, DM, 8), 256, 0, stream>>>(
        lnb_h, lnb_l, nullptr, m1Th, m1Tl, mask_b1, nullptr, pbuf, nullptr, nullptr, NQ, DM, DM);
    redsplit_kernel<1, 1><<<rgrid(NQ * DM), 256, 0, stream>>>(pbuf, nullptr, f1_h, f1_l, 8, NQ * DM);
    mgemm_kernel<1, 1, 1, 1, 0, 3, 8><<<g64(NQ, DM, 8), 256, 0, stream>>>(
        f1_h, f1_l, nullptr, m2Th, m2Tl, mask_b2, nullptr, pbuf, nullptr, nullptr, NQ, DM, DM);
    redsplit_kernel<1, 1><<<rgrid(NQ * DM), 256, 0, stream>>>(pbuf, nullptr, f2_h, f2_l, 8, NQ * DM);
    mgemm_kernel<1, 1, 1, 1, 0, 3, 8><<<g64(NQ, DM, 8), 256, 0, stream>>>(
        f2_h, f2_l, nullptr, m3Th, m3Tl, mask_b3, nullptr, pbuf, nullptr, nullptr, NQ, DM, DM);
    redsplit_kernel<0, 1><<<rgrid(NQ * DM), 256, 0, stream>>>(pbuf, nullptr, f3_h, f3_l, 8, NQ * DM);
    mgemm_kernel<1, 1, 1, 1, 0, 3, 4><<<g64(NQ, NPATCH, 4), 256, 0, stream>>>(
        f3_h, f3_l, nullptr, lnb_h + (size_t)(NQ + PFX) * DM, lnb_l + (size_t)(NQ + PFX) * DM,
        nullptr, nullptr, pbuf, nullptr, nullptr, NQ, NPATCH, DM);
    redsplit_kernel<0, 0><<<rgrid(NQ * NPATCH), 256, 0, stream>>>(
        pbuf, mask_i, nullptr, nullptr, 4, NQ * NPATCH);
    mgemm_kernel<1, 0, 1, 1, 0, 3, 8><<<g64(NQ, NCLS, 8), 256, 0, stream>>>(
        lnb_h, lnb_l, class_W, nullptr, nullptr, class_b, nullptr, pbuf, nullptr, nullptr, NQ, NCLS, DM);
    redsplit_kernel<0, 0><<<rgrid(NQ * NCLS), 256, 0, stream>>>(
        pbuf, cls_i, nullptr, nullptr, 8, NQ * NCLS);
    if (i == NBLK) break;

    // ---- transformer block i (weights pure bf16; outputs ls-damped into x) ----
    ln_kernel<<<NT, 256, 0, stream>>>(x, ln1_g + i * DM, ln1_b + i * DM, lnb_h, lnb_l);
    cvtT_kernel<0><<<cgrid(DM, 3 * DM), 256, 0, stream>>>(
        qkv_W + (size_t)i * DM * 3 * DM, qTh, qTl, DM, 3 * DM);
    mgemm_kernel<0, 1, 0, 0, 0, 7, 1><<<g128(NT, 3 * DM, 1), 256, 0, stream>>>(
        lnb_h, lnb_l, nullptr, qTh, qTl, qkv_b + i * 3 * DM, nullptr,
        (float*)vtb, qkvh, qkvl, NT, 3 * DM, DM);
    maskpack_kernel<<<(NQ * NWRD + 255) / 256, 256, 0, stream>>>(mask_i, bias_bits);
    fattn_kernel<<<NKT * NHEAD, 256, 0, stream>>>(qkvh, qkvl, vtb, bias_bits, aoh);
    cvtT_kernel<0><<<cgrid(DM, DM), 256, 0, stream>>>(
        proj_W + (size_t)i * DM * DM, pTh, pTl, DM, DM);
    mgemm_kernel<1, 1, 0, 0, 0, 5, 4><<<g64(NT, DM, 4), 256, 0, stream>>>(
        aoh, nullptr, nullptr, pTh, pTl, proj_b + i * DM, ls1 + i * DM,
        x, nullptr, nullptr, NT, DM, DM);
    ln_kernel<<<NT, 256, 0, stream>>>(x, ln2_g + i * DM, ln2_b + i * DM, lnb_h, lnb_l);
    cvtT_kernel<0><<<cgrid(DM, 4 * DM), 256, 0, stream>>>(
        fc1_W + (size_t)i * DM * 4 * DM, fTh, fTl, DM, 4 * DM);
    mgemm_kernel<0, 1, 0, 0, 1, 4, 1><<<g128(NT, 4 * DM, 1), 256, 0, stream>>>(
        lnb_h, lnb_l, nullptr, fTh, fTl, fc1_b + i * 4 * DM, nullptr,
        nullptr, g1h, nullptr, NT, 4 * DM, DM);
    cvtT_kernel<0><<<cgrid(4 * DM, DM), 256, 0, stream>>>(
        fc2_W + (size_t)i * 4 * DM * DM, fTh, fTl, 4 * DM, DM);
    mgemm_kernel<1, 1, 0, 0, 0, 5, 4><<<g64(NT, DM, 4), 256, 0, stream>>>(
        g1h, nullptr, nullptr, fTh, fTl, fc2_b + i * DM, ls2 + i * DM,
        x, nullptr, nullptr, NT, DM, 4 * DM);
  }
}